// Round 5
// baseline (371.316 us; speedup 1.0000x reference)
//
#include <hip/hip_runtime.h>
#include <cstdint>
#include <cstddef>

#define N_NODES 50000
#define E_EDGES 800000
#define IN_F    128
#define PCOLS   512   // P: [0,96) Y0 | [96,192) Zpre | [192,288) Zblk | [288,480) Zpost | pad

typedef unsigned short ushortT;
typedef unsigned int   uintT;
typedef __attribute__((ext_vector_type(8))) short s8v;   // 8 bf16 (4 VGPR)
typedef __attribute__((ext_vector_type(4))) float f4v;   // 4 fp32 acc

__device__ __forceinline__ float bflo(uintT u){ union{uintT i;float f;}c; c.i=u<<16; return c.f; }
__device__ __forceinline__ float bfhi(uintT u){ union{uintT i;float f;}c; c.i=u&0xFFFF0000u; return c.f; }
__device__ __forceinline__ ushortT f2bfu(float f){
    union{float f;uintT u;}c; c.f=f;
    uintT r = c.u + 0x7FFF + ((c.u>>16)&1);
    return (ushortT)(r>>16);
}
__device__ __forceinline__ uintT pack2(float a, float b){
    return (uintT)f2bfu(a) | ((uintT)f2bfu(b) << 16);
}
__device__ __forceinline__ float rdlane(float v, int sl){
    return __int_as_float(__builtin_amdgcn_readlane(__float_as_int(v), sl));
}

// ---------- pack weights: Wb [512][128] bf16 (gemm, transposed), bcat[512] fp32,
//            Wt1 [3][32][32] fp32 (W_blk^T per group), Wt2 [3][64][32] fp32 (W_post^T) ----------
__global__ void pack_weights(const float* __restrict__ Wp,  const float* __restrict__ bp,
                             const float* __restrict__ Tp,  const float* __restrict__ bTp,
                             const float* __restrict__ Tb,  const float* __restrict__ bTb,
                             const float* __restrict__ Tpo, const float* __restrict__ bTpo,
                             const float* __restrict__ Wblk, const float* __restrict__ Wpost,
                             ushortT* __restrict__ Wb, float* __restrict__ bcat,
                             float* __restrict__ Wt1, float* __restrict__ Wt2)
{
    int id = blockIdx.x * 256 + threadIdx.x;
    if (id >= IN_F * PCOLS) return;
    int k = id >> 9;
    int c = id & 511;
    float v;
    if      (c < 96)  v = Wp [k*96  + c];
    else if (c < 192) v = Tp [k*96  + (c-96)];
    else if (c < 288) v = Tb [k*96  + (c-192)];
    else if (c < 480) v = Tpo[k*192 + (c-288)];
    else              v = 0.f;
    Wb[(size_t)c*IN_F + k] = f2bfu(v);
    if (k == 0) {
        float b;
        if      (c < 96)  b = bp  [c];
        else if (c < 192) b = bTp [c-96];
        else if (c < 288) b = bTb [c-192];
        else if (c < 480) b = bTpo[c-288];
        else              b = 0.f;
        bcat[c] = b;
    }
    if (id < 3*32*32) {               // W_blk[w][i][j] -> Wt1[(w*32+j)*32+i]
        int w = id >> 10, r = id & 1023;
        int i = r >> 5, j = r & 31;
        Wt1[(w*32 + j)*32 + i] = Wblk[id];
    }
    if (id < 3*32*64) {               // W_post[w][i][j] -> Wt2[(w*64+j)*32+i]
        int w = id >> 11, r = id & 2047;
        int i = r >> 6, j = r & 63;
        Wt2[(w*64 + j)*32 + i] = Wpost[id];
    }
}

// ---------- convert data fp32 -> Ab bf16 [N][128] ----------
__global__ void convert_data(const float* __restrict__ A, ushortT* __restrict__ Ab)
{
    int gid = blockIdx.x * 256 + threadIdx.x;
    size_t off = (size_t)gid * 8;
    float4 v0 = *(const float4*)(A + off);
    float4 v1 = *(const float4*)(A + off + 4);
    uint4 u;
    u.x = pack2(v0.x, v0.y); u.y = pack2(v0.z, v0.w);
    u.z = pack2(v1.x, v1.y); u.w = pack2(v1.z, v1.w);
    *(uint4*)(Ab + off) = u;
}

// ---------- row_ptr via binary search on sorted tgt ----------
__global__ void build_row_ptr(const int* __restrict__ tgt, int* __restrict__ row_ptr,
                              int E, int Np1)
{
    int t = blockIdx.x * 256 + threadIdx.x;
    if (t >= Np1) return;
    int lo = 0, hi = E;
    while (lo < hi) {
        int mid = (lo + hi) >> 1;
        if (tgt[mid] < t) lo = mid + 1; else hi = mid;
    }
    row_ptr[t] = lo;
}

// ---------- MFMA GEMM: P[M,512] = Ab[M,128] @ Wb^T + bcat ; also emit Y0b bf16 ----------
__global__ __launch_bounds__(256, 2) void gemm_mfma(const ushortT* __restrict__ Ab,
                                                    const ushortT* __restrict__ Wb,
                                                    const float* __restrict__ bcat,
                                                    float* __restrict__ P,
                                                    ushortT* __restrict__ Y0b, int M)
{
    __shared__ ushortT Asl[128][72];
    __shared__ ushortT Bsl[128][72];
    int tid = threadIdx.x;
    int nb = blockIdx.x * 128;
    int mb = blockIdx.y * 128;
    int wv = tid >> 6, lane = tid & 63;
    int wm = wv >> 1, wn = wv & 1;
    int cl = lane & 15, q = lane >> 4;

    f4v acc[4][4];
    #pragma unroll
    for (int i = 0; i < 4; ++i)
        #pragma unroll
        for (int j = 0; j < 4; ++j) acc[i][j] = (f4v)0.f;

    for (int kt = 0; kt < IN_F; kt += 64) {
        if (kt) __syncthreads();
        #pragma unroll
        for (int r = 0; r < 4; ++r) {
            int idx = tid + 256*r;
            int row = idx >> 3, qq = idx & 7;
            int gm = mb + row;
            uint4 v = make_uint4(0,0,0,0);
            if (gm < M) v = *(const uint4*)(Ab + (size_t)gm*IN_F + kt + qq*8);
            *(uint4*)(&Asl[row][qq*8]) = v;
        }
        #pragma unroll
        for (int r = 0; r < 4; ++r) {
            int idx = tid + 256*r;
            int row = idx >> 3, qq = idx & 7;
            uint4 v = *(const uint4*)(Wb + (size_t)(nb+row)*IN_F + kt + qq*8);
            *(uint4*)(&Bsl[row][qq*8]) = v;
        }
        __syncthreads();
        #pragma unroll
        for (int ks = 0; ks < 2; ++ks) {
            int ko = ks*32 + q*8;
            s8v af[4], bf[4];
            #pragma unroll
            for (int mt = 0; mt < 4; ++mt)
                af[mt] = *(const s8v*)(&Asl[wm*64 + mt*16 + cl][ko]);
            #pragma unroll
            for (int nt = 0; nt < 4; ++nt)
                bf[nt] = *(const s8v*)(&Bsl[wn*64 + nt*16 + cl][ko]);
            #pragma unroll
            for (int mt = 0; mt < 4; ++mt)
                #pragma unroll
                for (int nt = 0; nt < 4; ++nt)
                    acc[mt][nt] = __builtin_amdgcn_mfma_f32_16x16x32_bf16(af[mt], bf[nt], acc[mt][nt], 0, 0, 0);
        }
    }

    bool y0blk = (nb == 0) && (wn == 0);
    #pragma unroll
    for (int nt = 0; nt < 4; ++nt) {
        int gn = nb + wn*64 + nt*16 + cl;
        float bv = bcat[gn];
        bool doY = y0blk && (gn < 96);
        #pragma unroll
        for (int mt = 0; mt < 4; ++mt) {
            int gm0 = mb + wm*64 + mt*16 + q*4;
            #pragma unroll
            for (int r = 0; r < 4; ++r) {
                int gm = gm0 + r;
                if (gm < M) {
                    float val = acc[mt][nt][r] + bv;
                    P[(size_t)gm*PCOLS + gn] = val;
                    if (doY) Y0b[(size_t)gm*96 + gn] = f2bfu(val);
                }
            }
        }
    }
}

// ---------- fused lap + grouped conv, LDS-free ----------
// Wave per node; lane L holds feats {2L,2L+1} (L<48). Conv: lane L<HO computes
// channels HO*t+L via register weights + v_readlane act broadcast (group uniform/chunk).
#define CPB 20
#define GRID_AB (N_NODES / CPB)   // 2500

template<int HO>   // 32 (blk) or 64 (post)
__global__ __launch_bounds__(256) void lap_conv(
    const ushortT* __restrict__ Xb,     // [N,96] bf16 gather source
    const float*   __restrict__ Pown,   // fp32 own-x ([N,512] cols 0..95) or null
    const float*   __restrict__ Z,      // [N,512] + col offset applied
    const int* __restrict__ src, const int* __restrict__ row_ptr,
    const float* __restrict__ Wt,       // [3][HO][32] fp32 transposed
    const float* __restrict__ bg,       // [3*HO]
    ushortT* __restrict__ outb)         // [N, 3*HO] bf16
{
    int wv = threadIdx.x >> 6, lane = threadIdx.x & 63;
    int pL = lane < 48 ? lane : 0;
    int wl = lane < HO ? lane : 0;

    // weights -> registers: lane L holds Wt[t][L][0..31], t=0..2
    float wreg[96];
    float breg[3];
    #pragma unroll
    for (int t2 = 0; t2 < 3; ++t2) {
        breg[t2] = bg[t2*HO + wl];
        const float4* sp = (const float4*)(Wt + (size_t)(t2*HO + wl)*32);
        #pragma unroll
        for (int q8 = 0; q8 < 8; ++q8) {
            float4 v = sp[q8];
            wreg[t2*32 + q8*4 + 0] = v.x;
            wreg[t2*32 + q8*4 + 1] = v.y;
            wreg[t2*32 + q8*4 + 2] = v.z;
            wreg[t2*32 + q8*4 + 3] = v.w;
        }
    }

    #pragma unroll 1
    for (int trip = 0; trip < CPB/4; ++trip) {
        int t  = __builtin_amdgcn_readfirstlane(blockIdx.x * CPB + wv + 4*trip);
        int lo = __builtin_amdgcn_readfirstlane(row_ptr[t]);
        int hi = __builtin_amdgcn_readfirstlane(row_ptr[t+1]);
        // hoisted own-x and Z
        float xx, xy;
        if (Pown) {
            float2 xr = *(const float2*)(Pown + (size_t)t*PCOLS + 2*pL);
            xx = xr.x; xy = xr.y;
        } else {
            uintT ux = *(const uintT*)(Xb + (size_t)t*96 + 2*pL);
            xx = bflo(ux); xy = bfhi(ux);
        }
        float2 zr = *(const float2*)(Z + (size_t)t*PCOLS + 2*pL);

        float c0x=0.f,c0y=0.f,c1x=0.f,c1y=0.f,c2x=0.f,c2y=0.f,c3x=0.f,c3y=0.f;
        int j = lo;
        #pragma unroll 1
        for (; j + 8 <= hi; j += 8) {
            int i0 = src[j+0], i1 = src[j+1], i2 = src[j+2], i3 = src[j+3];
            int i4 = src[j+4], i5 = src[j+5], i6 = src[j+6], i7 = src[j+7];
            uintT u0 = *(const uintT*)(Xb + (size_t)i0*96 + 2*pL);
            uintT u1 = *(const uintT*)(Xb + (size_t)i1*96 + 2*pL);
            uintT u2 = *(const uintT*)(Xb + (size_t)i2*96 + 2*pL);
            uintT u3 = *(const uintT*)(Xb + (size_t)i3*96 + 2*pL);
            uintT u4 = *(const uintT*)(Xb + (size_t)i4*96 + 2*pL);
            uintT u5 = *(const uintT*)(Xb + (size_t)i5*96 + 2*pL);
            uintT u6 = *(const uintT*)(Xb + (size_t)i6*96 + 2*pL);
            uintT u7 = *(const uintT*)(Xb + (size_t)i7*96 + 2*pL);
            c0x += bflo(u0); c0y += bfhi(u0);
            c1x += bflo(u1); c1y += bfhi(u1);
            c2x += bflo(u2); c2y += bfhi(u2);
            c3x += bflo(u3); c3y += bfhi(u3);
            c0x += bflo(u4); c0y += bfhi(u4);
            c1x += bflo(u5); c1y += bfhi(u5);
            c2x += bflo(u6); c2y += bfhi(u6);
            c3x += bflo(u7); c3y += bfhi(u7);
        }
        #pragma unroll 1
        for (; j < hi; ++j) {
            int i0 = src[j];
            uintT u0 = *(const uintT*)(Xb + (size_t)i0*96 + 2*pL);
            c0x += bflo(u0); c0y += bfhi(u0);
        }
        float sx = (c0x+c1x)+(c2x+c3x);
        float sy = (c0y+c1y)+(c2y+c3y);
        int deg = hi - lo;
        float inv = deg > 0 ? 1.f/(float)deg : 0.f;
        float mf  = deg > 0 ? 1.f : 0.f;
        float ox = fmaxf(mf*xx - sx*inv + zr.x, 0.f);   // feat 2pL
        float oy = fmaxf(mf*xy - sy*inv + zr.y, 0.f);   // feat 2pL+1

        // conv: chunk t2 -> group w=t2 uniform; act f=32*t2+i lives in lane 16*t2+i/2
        #pragma unroll
        for (int t2 = 0; t2 < 3; ++t2) {
            float acc = breg[t2];
            #pragma unroll
            for (int i = 0; i < 32; i += 2) {
                int sl = 16*t2 + (i >> 1);
                float ax = rdlane(ox, sl);
                float ay = rdlane(oy, sl);
                acc = fmaf(ax, wreg[t2*32 + i],     acc);
                acc = fmaf(ay, wreg[t2*32 + i + 1], acc);
            }
            if (lane < HO) outb[(size_t)t*(3*HO) + HO*t2 + lane] = f2bfu(acc);
        }
    }
}

// ---------- final: relu(Lap(h2b)+Zpost), width-mean via shfl -> out[N,64] ----------
__global__ void lap_final(const ushortT* __restrict__ Xb,  // [N,192] bf16
                          const float* __restrict__ Z,     // P + 288
                          const int* __restrict__ src, const int* __restrict__ row_ptr,
                          float* __restrict__ out, int N)
{
    int lane = threadIdx.x & 63;
    int wid  = __builtin_amdgcn_readfirstlane(
                   (int)(((size_t)blockIdx.x * blockDim.x + threadIdx.x) >> 6));
    if (wid >= N) return;
    int lo = __builtin_amdgcn_readfirstlane(row_ptr[wid]);
    int hi = __builtin_amdgcn_readfirstlane(row_ptr[wid+1]);
    int pL2 = lane & 31;
    uintT uxa = *(const uintT*)(Xb + (size_t)wid*192 + 2*lane);
    uintT uxb = *(const uintT*)(Xb + (size_t)wid*192 + 128 + 2*pL2);
    float2 za  = *(const float2*)(Z + (size_t)wid*PCOLS + 2*lane);
    float2 zb  = *(const float2*)(Z + (size_t)wid*PCOLS + 128 + 2*pL2);

    float a0x=0,a0y=0,a1x=0,a1y=0;     // feats 2L,2L+1 (two chains)
    float b0x=0,b0y=0,b1x=0,b1y=0;     // feats 128+2L'
    int j = lo;
    #pragma unroll 1
    for (; j + 8 <= hi; j += 8) {
        int i0 = src[j+0], i1 = src[j+1], i2 = src[j+2], i3 = src[j+3];
        int i4 = src[j+4], i5 = src[j+5], i6 = src[j+6], i7 = src[j+7];
        const ushortT *r0 = Xb + (size_t)i0*192, *r1 = Xb + (size_t)i1*192;
        const ushortT *r2 = Xb + (size_t)i2*192, *r3 = Xb + (size_t)i3*192;
        const ushortT *r4 = Xb + (size_t)i4*192, *r5 = Xb + (size_t)i5*192;
        const ushortT *r6 = Xb + (size_t)i6*192, *r7 = Xb + (size_t)i7*192;
        uintT ua0 = *(const uintT*)(r0 + 2*lane), ub0 = *(const uintT*)(r0 + 128 + 2*pL2);
        uintT ua1 = *(const uintT*)(r1 + 2*lane), ub1 = *(const uintT*)(r1 + 128 + 2*pL2);
        uintT ua2 = *(const uintT*)(r2 + 2*lane), ub2 = *(const uintT*)(r2 + 128 + 2*pL2);
        uintT ua3 = *(const uintT*)(r3 + 2*lane), ub3 = *(const uintT*)(r3 + 128 + 2*pL2);
        uintT ua4 = *(const uintT*)(r4 + 2*lane), ub4 = *(const uintT*)(r4 + 128 + 2*pL2);
        uintT ua5 = *(const uintT*)(r5 + 2*lane), ub5 = *(const uintT*)(r5 + 128 + 2*pL2);
        uintT ua6 = *(const uintT*)(r6 + 2*lane), ub6 = *(const uintT*)(r6 + 128 + 2*pL2);
        uintT ua7 = *(const uintT*)(r7 + 2*lane), ub7 = *(const uintT*)(r7 + 128 + 2*pL2);
        a0x += bflo(ua0); a0y += bfhi(ua0); b0x += bflo(ub0); b0y += bfhi(ub0);
        a1x += bflo(ua1); a1y += bfhi(ua1); b1x += bflo(ub1); b1y += bfhi(ub1);
        a0x += bflo(ua2); a0y += bfhi(ua2); b0x += bflo(ub2); b0y += bfhi(ub2);
        a1x += bflo(ua3); a1y += bfhi(ua3); b1x += bflo(ub3); b1y += bfhi(ub3);
        a0x += bflo(ua4); a0y += bfhi(ua4); b0x += bflo(ub4); b0y += bfhi(ub4);
        a1x += bflo(ua5); a1y += bfhi(ua5); b1x += bflo(ub5); b1y += bfhi(ub5);
        a0x += bflo(ua6); a0y += bfhi(ua6); b0x += bflo(ub6); b0y += bfhi(ub6);
        a1x += bflo(ua7); a1y += bfhi(ua7); b1x += bflo(ub7); b1y += bfhi(ub7);
    }
    #pragma unroll 1
    for (; j < hi; ++j) {
        int i0 = src[j];
        const ushortT* r0 = Xb + (size_t)i0*192;
        uintT ua0 = *(const uintT*)(r0 + 2*lane);
        uintT ub0 = *(const uintT*)(r0 + 128 + 2*pL2);
        a0x += bflo(ua0); a0y += bfhi(ua0);
        b0x += bflo(ub0); b0y += bfhi(ub0);
    }
    float sax = a0x + a1x, say = a0y + a1y;
    float sbx = b0x + b1x, sby = b0y + b1y;
    int deg = hi - lo;
    float inv = deg > 0 ? 1.f/(float)deg : 0.f;
    float mf  = deg > 0 ? 1.f : 0.f;
    float2 oa, ob;
    oa.x = fmaxf(mf*bflo(uxa) - sax*inv + za.x, 0.f);
    oa.y = fmaxf(mf*bfhi(uxa) - say*inv + za.y, 0.f);
    ob.x = fmaxf(mf*bflo(uxb) - sbx*inv + zb.x, 0.f);
    ob.y = fmaxf(mf*bfhi(uxb) - sby*inv + zb.y, 0.f);
    float r = 0.f;
    #pragma unroll
    for (int qq = 0; qq < 3; ++qq) {
        int g  = 3*lane + qq;
        int pa = (g >> 1) & 63;
        int pb = ((g - 128) >> 1) & 63;
        float cax = __shfl(oa.x, pa), cay = __shfl(oa.y, pa);
        float cbx = __shfl(ob.x, pb), cby = __shfl(ob.y, pb);
        float v = (g < 128) ? ((g & 1) ? cay : cax)
                            : ((g & 1) ? cby : cbx);
        r += v;
    }
    out[(size_t)wid*64 + lane] = r * (1.0f/3.0f);
}

extern "C" void kernel_launch(void* const* d_in, const int* in_sizes, int n_in,
                              void* d_out, int out_size, void* d_ws, size_t ws_size,
                              hipStream_t stream)
{
    const float* data    = (const float*)d_in[0];
    const int*   src     = (const int*)  d_in[1];
    const int*   tgt     = (const int*)  d_in[2];
    const float* W_pre   = (const float*)d_in[3];
    const float* b_pre   = (const float*)d_in[4];
    const float* T_pre   = (const float*)d_in[5];
    const float* bT_pre  = (const float*)d_in[6];
    const float* W_blk   = (const float*)d_in[7];
    const float* b_blk   = (const float*)d_in[8];
    const float* T_blk   = (const float*)d_in[9];
    const float* bT_blk  = (const float*)d_in[10];
    const float* W_post  = (const float*)d_in[11];
    const float* b_post  = (const float*)d_in[12];
    const float* T_post  = (const float*)d_in[13];
    const float* bT_post = (const float*)d_in[14];
    float* out = (float*)d_out;

    float* ws = (float*)d_ws;
    float*   P       = ws;                                  // N*512 f32
    float*   bcat    = P + (size_t)N_NODES * PCOLS;         // 512
    float*   Wt1     = bcat + 512;                          // 3*32*32
    float*   Wt2     = Wt1 + 3*32*32;                       // 3*64*32
    int*     row_ptr = (int*)(Wt2 + 3*64*32);               // 50008 ints
    ushortT* Y0b     = (ushortT*)(row_ptr + 50008);         // N*96 bf16
    ushortT* h1b     = Y0b + (size_t)N_NODES * 96;          // N*96 bf16
    ushortT* h2b     = h1b + (size_t)N_NODES * 96;          // N*192 bf16
    ushortT* Ab      = h2b + (size_t)N_NODES * 192;         // N*128 bf16
    ushortT* Wb      = Ab  + (size_t)N_NODES * IN_F;        // 512*128 bf16

    pack_weights<<<(IN_F*PCOLS + 255)/256, 256, 0, stream>>>(
        W_pre, b_pre, T_pre, bT_pre, T_blk, bT_blk, T_post, bT_post,
        W_blk, W_post, Wb, bcat, Wt1, Wt2);

    convert_data<<<(N_NODES*IN_F/8 + 255)/256, 256, 0, stream>>>(data, Ab);

    build_row_ptr<<<(N_NODES + 1 + 255)/256, 256, 0, stream>>>(tgt, row_ptr, E_EDGES, N_NODES + 1);

    dim3 gg(PCOLS/128, (N_NODES + 127)/128);
    gemm_mfma<<<gg, 256, 0, stream>>>(Ab, Wb, bcat, P, Y0b, N_NODES);

    // layer 1 + conv_blk -> h1b
    lap_conv<32><<<GRID_AB, 256, 0, stream>>>(Y0b, P, P + 96, src, row_ptr, Wt1, b_blk, h1b);
    // layer 2 + conv_post -> h2b
    lap_conv<64><<<GRID_AB, 256, 0, stream>>>(h1b, nullptr, P + 192, src, row_ptr, Wt2, b_post, h2b);
    // layer 3 + width-mean
    lap_final<<<(N_NODES*64)/256, 256, 0, stream>>>(h2b, P + 288, src, row_ptr, out, N_NODES);
}